// Round 5
// baseline (539.254 us; speedup 1.0000x reference)
//
#include <hip/hip_runtime.h>

#define NN 256
#define CC 16
#define OC 288          // 18*16 output channels (72 float4)

typedef unsigned long long u64;
typedef unsigned int u32;

__device__ __forceinline__ void add4(float4& a, const float4 b) {
    a.x += b.x; a.y += b.y; a.z += b.z; a.w += b.w;
}

// position of i-th set bit of m (valid when i < popc(m)); branchless binary search
__device__ __forceinline__ int nthbit(u32 m, int i) {
    int pos = 0, c;
    c = __popc(m & 0xFFFFu); if (i >= c) { i -= c; pos = 16; m >>= 16; }
    c = __popc(m & 0xFFu);   if (i >= c) { i -= c; pos += 8; m >>= 8; }
    c = __popc(m & 0xFu);    if (i >= c) { i -= c; pos += 4; m >>= 4; }
    c = __popc(m & 0x3u);    if (i >= c) { i -= c; pos += 2; m >>= 2; }
    if (i >= (int)(m & 1u)) pos += 1;
    return pos;
}

// ---------------- K0: neighbor lists + bitmasks ----------------
__global__ void k_build_nbr(const float* __restrict__ A, short* __restrict__ nbr,
                            int* __restrict__ deg, u64* __restrict__ umask) {
    int a = blockIdx.x;
    int t = threadIdx.x;            // 0..255
    int lane = t & 63, wave = t >> 6;
    bool pred = A[a*NN + t] != 0.0f;
    u64 m = __ballot(pred);
    __shared__ int wcnt[4];
    if (lane == 0) { wcnt[wave] = __popcll(m); umask[a*4 + wave] = m; }
    __syncthreads();
    int off = 0;
    for (int w = 0; w < wave; ++w) off += wcnt[w];
    if (pred) {
        int pos = off + __popcll(m & ((1ull << lane) - 1ull));
        nbr[a*NN + pos] = (short)t;
    }
    if (t == 0) deg[a] = wcnt[0] + wcnt[1] + wcnt[2] + wcnt[3];
}

// ---------------- K_slab2: c1,c2,c3,c4 + c7..c12 from slab a ----------------
// 256 blocks x 1024 threads (16 waves, 4/SIMD). Wave w owns rows j = w, w+16, ...
// Per row (a,j): walk union mask N(a)|N(j)|{a,j} (full row if j==a or A[a,j]);
// group g (4 lanes) loads the (p*16+g)-th set chunk. c1/c2 reduce in-register +
// one butterfly per row. c3/c4 accumulate via LDS atomicAdd (rare collisions).
__global__ __launch_bounds__(1024) void k_slab2(const float4* __restrict__ T4,
                                                const u64* __restrict__ umask,
                                                float4* __restrict__ out4) {
    int a = blockIdx.x;
    int t = threadIdx.x;
    int w = t >> 6, lane = t & 63, g = lane >> 2, v = lane & 3;

    __shared__ u64   masks8[NN][4];      // 8 KB
    __shared__ float c3a[NN*17];         // 17.4 KB (chunk stride 17 floats: bank spread)
    __shared__ float c4a[NN*17];         // 17.4 KB

    for (int idx = t; idx < NN*4; idx += 1024) ((u64*)masks8)[idx] = umask[idx];
    for (int idx = t; idx < NN*17; idx += 1024) { c3a[idx] = 0.f; c4a[idx] = 0.f; }
    __syncthreads();

    u32 NA[8];
    #pragma unroll
    for (int u = 0; u < 4; ++u) {
        u64 m = masks8[a][u];
        NA[2*u] = (u32)m; NA[2*u+1] = (u32)(m >> 32);
    }
    const float4* slab = T4 + ((size_t)a << 18);

    for (int j = w; j < NN; j += 16) {
        u32 NJ[8], U[8];
        #pragma unroll
        for (int u = 0; u < 4; ++u) {
            u64 m = masks8[j][u];
            NJ[2*u] = (u32)m; NJ[2*u+1] = (u32)(m >> 32);
        }
        bool isnbr = (masks8[a][j >> 6] >> (j & 63)) & 1ull;
        bool full  = isnbr || (j == a);
        #pragma unroll
        for (int ww = 0; ww < 8; ++ww) {
            u32 uu = NA[ww] | NJ[ww];
            uu |= (ww == (a >> 5)) ? (1u << (a & 31)) : 0u;
            uu |= (ww == (j >> 5)) ? (1u << (j & 31)) : 0u;
            U[ww] = full ? 0xFFFFFFFFu : uu;
        }

        const float4* row = slab + ((size_t)j << 10);
        float4 r1 = {0,0,0,0}, r2 = {0,0,0,0};
        size_t opq = (size_t)(a*NN + j) * 72;
        size_t oqp = (size_t)(j*NN + a) * 72;

        #pragma unroll
        for (int ww = 0; ww < 8; ++ww) {
            u32 mw = U[ww];
            int nb = __popc(mw);
            for (int p = 0; p*16 < nb; ++p) {
                int n = p*16 + g;
                bool va = n < nb;
                int pos = nthbit(mw, va ? n : 0);
                int k = ww*32 + pos;
                float4 x = {0,0,0,0};
                if (va) x = row[(k << 2) + v];
                bool inA = va && ((NA[ww] >> pos) & 1u);
                bool inJ = va && ((NJ[ww] >> pos) & 1u);
                if (inA) add4(r1, x);
                if (inJ) add4(r2, x);
                if (isnbr && va) {
                    atomicAdd(&c3a[k*17 + v*4 + 0], x.x);
                    atomicAdd(&c3a[k*17 + v*4 + 1], x.y);
                    atomicAdd(&c3a[k*17 + v*4 + 2], x.z);
                    atomicAdd(&c3a[k*17 + v*4 + 3], x.w);
                }
                if (inJ) {
                    atomicAdd(&c4a[k*17 + v*4 + 0], x.x);
                    atomicAdd(&c4a[k*17 + v*4 + 1], x.y);
                    atomicAdd(&c4a[k*17 + v*4 + 2], x.z);
                    atomicAdd(&c4a[k*17 + v*4 + 3], x.w);
                }
                if (va && k == a) { out4[opq + 32 + v] = x;   // c9  (a,j)
                                    out4[oqp + 36 + v] = x; } // c10 (j,a)
                if (va && k == j) { out4[opq + 40 + v] = x;   // c11 (a,j)
                                    out4[oqp + 44 + v] = x; } // c12 (j,a)
                if (j == a && va) {
                    out4[(size_t)(a*NN + k)*72 + 24 + v] = x; // c7  (a,k)
                    out4[(size_t)(k*NN + a)*72 + 28 + v] = x; // c8  (k,a)
                }
            }
        }

        // butterfly across the 16 lane-groups (lane bits 2..5)
        #pragma unroll
        for (int off = 4; off < 64; off <<= 1) {
            r1.x += __shfl_xor(r1.x, off); r1.y += __shfl_xor(r1.y, off);
            r1.z += __shfl_xor(r1.z, off); r1.w += __shfl_xor(r1.w, off);
            r2.x += __shfl_xor(r2.x, off); r2.y += __shfl_xor(r2.y, off);
            r2.z += __shfl_xor(r2.z, off); r2.w += __shfl_xor(r2.w, off);
        }
        if (g == 0) out4[opq + 0 + v] = r1;   // c1[a,j]
        if (g == 1) out4[oqp + 4 + v] = r2;   // c2[j,a]
    }

    __syncthreads();
    // flush c3[a,.] (ch2) and c4[.,a] (ch3)
    for (int idx = t; idx < NN*4; idx += 1024) {
        int k = idx >> 2, vv = idx & 3;
        float4 x3 = {c3a[k*17+vv*4+0], c3a[k*17+vv*4+1], c3a[k*17+vv*4+2], c3a[k*17+vv*4+3]};
        float4 x4 = {c4a[k*17+vv*4+0], c4a[k*17+vv*4+1], c4a[k*17+vv*4+2], c4a[k*17+vv*4+3]};
        out4[(size_t)(a*NN + k)*72 + 8  + vv] = x3;
        out4[(size_t)(k*NN + a)*72 + 12 + vv] = x4;
    }
}

// ---------------- K_col: c5, c6 ----------------
// block = (a, b-quarter): 1024 blocks x 256 threads.
__global__ __launch_bounds__(256) void k_col(const float4* __restrict__ T4,
                                             const short* __restrict__ nbr,
                                             const int* __restrict__ deg,
                                             float4* __restrict__ out4) {
    int a = blockIdx.x >> 2;
    int qq = blockIdx.x & 3;
    int t = threadIdx.x;
    int g = t >> 2, v = t & 3;
    int d = deg[a];
    __shared__ short nbs[NN];
    for (int e = t; e < d; e += 256) nbs[e] = nbr[a*NN + e];
    __syncthreads();

    const int b = qq*64 + g;
    const int qslot = qq*256 + t;
    float4 a5 = {0,0,0,0};
    float4 a6 = {0,0,0,0};
    #pragma unroll 2
    for (int e = 0; e < d; ++e) {
        int i = nbs[e];
        float4 x5 = T4[((size_t)(i*NN + a) << 10) + qslot];           // T[i,a,b,:]
        float4 x6 = T4[((size_t)i << 18) + (b << 10) + (a << 2) + v]; // T[i,b,a,:]
        add4(a5, x5); add4(a6, x6);
    }
    size_t o = (size_t)(a*NN + b) * 72;
    out4[o + 16 + v] = a5;    // c5
    out4[o + 20 + v] = a6;    // c6
}

// ---------------- K_V: v1,v2,v3 from materialized c1,c2,c6 ----------------
__global__ void k_vsum(const float* __restrict__ out_ro,
                       const short* __restrict__ nbr, const int* __restrict__ deg,
                       float* __restrict__ vbuf) {
    int a = blockIdx.x;
    int t = threadIdx.x;            // 256
    int c = t & 15, p = t >> 4;
    int d = deg[a];
    float s1 = 0.f, s2 = 0.f, s3 = 0.f;
    for (int e = p; e < d; e += 16) {
        int b = nbr[a*NN + e];
        size_t o = (size_t)(a*NN + b) * OC;
        s1 += out_ro[o + 0  + c];   // c1
        s2 += out_ro[o + 16 + c];   // c2
        s3 += out_ro[o + 80 + c];   // c6
    }
    __shared__ float red[3][16][17];
    red[0][p][c] = s1; red[1][p][c] = s2; red[2][p][c] = s3;
    __syncthreads();
    if (t < 48) {
        int vv = t >> 4, cc = t & 15;
        float s = 0.f;
        for (int pp = 0; pp < 16; ++pp) s += red[vv][pp][cc];
        vbuf[(vv*NN + a)*CC + cc] = s;
    }
}

// ---------------- K_C: broadcast v's into channels 12..17 ----------------
__global__ __launch_bounds__(256) void k_broadcast(const float4* __restrict__ vb4,
                                                   float4* __restrict__ out4) {
    int a = blockIdx.x;
    int t = threadIdx.x;
    int v = t & 3, bl = t >> 2;
    float4 v1a = vb4[(0*NN + a)*4 + v];
    float4 v2a = vb4[(1*NN + a)*4 + v];
    float4 v3a = vb4[(2*NN + a)*4 + v];
    for (int b = bl; b < NN; b += 64) {
        float4 v1b = vb4[(0*NN + b)*4 + v];
        float4 v2b = vb4[(1*NN + b)*4 + v];
        float4 v3b = vb4[(2*NN + b)*4 + v];
        size_t ob = (size_t)(a*NN + b) * 72;
        out4[ob + 48 + v] = v1a;   // c13
        out4[ob + 52 + v] = v1b;   // c14
        out4[ob + 56 + v] = v2a;   // c15
        out4[ob + 60 + v] = v2b;   // c16
        out4[ob + 64 + v] = v3a;   // c17
        out4[ob + 68 + v] = v3b;   // c18
    }
}

extern "C" void kernel_launch(void* const* d_in, const int* in_sizes, int n_in,
                              void* d_out, int out_size, void* d_ws, size_t ws_size,
                              hipStream_t stream) {
    const float* T = (const float*)d_in[0];   // (256,256,256,16) f32
    const float* A = (const float*)d_in[1];   // (256,256) f32 {0,1} symmetric
    float* out = (float*)d_out;

    // ws: umask u64[256][4] | nbr short[256*256] | deg int[256] | vbuf f32[3*256*16]
    char* w = (char*)d_ws;
    u64*   umask = (u64*)w;                   w += NN*4*sizeof(u64);
    short* nbr   = (short*)w;                 w += NN*NN*sizeof(short);
    int*   deg   = (int*)w;                   w += NN*sizeof(int);
    float* vbuf  = (float*)w;

    hipLaunchKernelGGL(k_build_nbr, dim3(NN),   dim3(NN),   0, stream, A, nbr, deg, umask);
    hipLaunchKernelGGL(k_slab2,     dim3(NN),   dim3(1024), 0, stream,
                       (const float4*)T, umask, (float4*)out);
    hipLaunchKernelGGL(k_col,       dim3(NN*4), dim3(256),  0, stream,
                       (const float4*)T, nbr, deg, (float4*)out);
    hipLaunchKernelGGL(k_vsum,      dim3(NN),   dim3(256),  0, stream, out, nbr, deg, vbuf);
    hipLaunchKernelGGL(k_broadcast, dim3(NN),   dim3(256),  0, stream,
                       (const float4*)vbuf, (float4*)out);
}

// Round 6
// 319.718 us; speedup vs baseline: 1.6867x; 1.6867x over previous
//
#include <hip/hip_runtime.h>

#define NN 256
#define CC 16
#define OC 288          // 18*16 output channels (72 float4)

typedef unsigned long long u64;

__device__ __forceinline__ void add4(float4& a, const float4 b) {
    a.x += b.x; a.y += b.y; a.z += b.z; a.w += b.w;
}

// ---------------- K0: neighbor lists ----------------
__global__ void k_build_nbr(const float* __restrict__ A, short* __restrict__ nbr,
                            int* __restrict__ deg) {
    int a = blockIdx.x;
    int t = threadIdx.x;            // 0..255
    int lane = t & 63, wave = t >> 6;
    bool pred = A[a*NN + t] != 0.0f;
    u64 m = __ballot(pred);
    __shared__ int wcnt[4];
    if (lane == 0) wcnt[wave] = __popcll(m);
    __syncthreads();
    int off = 0;
    for (int w = 0; w < wave; ++w) off += wcnt[w];
    if (pred) {
        int pos = off + __popcll(m & ((1ull << lane) - 1ull));
        nbr[a*NN + pos] = (short)t;
    }
    if (t == 0) deg[a] = wcnt[0] + wcnt[1] + wcnt[2] + wcnt[3];
}

// ---------------- K_slab3: c1,c2,c4 + c7..c12 (slab p) ----------------
// 256 blocks x 1024 threads = 256 groups of 4 lanes; group g owns row j=g.
// Two UNCONDITIONAL gather loops per row (R2-style — no masks, no nthbit):
//   loop over nbr[p]: c1[p,j] row-reduce.
//   loop over nbr[j]: c2[j,p] row-reduce AND c4[m,p] via ds_add_f32 (the
//     chunk sets are identical -> c4 costs zero extra fetch).
// Diagonals c9..c12 = 2 extra chunks/row; c7/c8 = row (p,p) dense, block-wide.
__global__ __launch_bounds__(1024) void k_slab3(const float4* __restrict__ T4,
                                                const short* __restrict__ nbr,
                                                const int* __restrict__ deg,
                                                float4* __restrict__ out4) {
    const int p = blockIdx.x;
    const int t = threadIdx.x;
    const int g = t >> 2, v = t & 3;     // group g = row j

    __shared__ float c4a[NN*17];         // 17 KB, chunk m at c4a[m*17 + v*4 + .]
    __shared__ short nbsP[NN];
    __shared__ int   degs[NN];

    for (int idx = t; idx < NN*17; idx += 1024) c4a[idx] = 0.f;
    if (t < NN) degs[t] = deg[t];
    const int dp = deg[p];
    for (int e = t; e < dp; e += 1024) nbsP[e] = nbr[p*NN + e];
    __syncthreads();

    const int j = g;
    const float4* row = T4 + (((size_t)(p*NN + j)) << 10);
    const int dj = degs[j];
    const short* nbJ = nbr + j*NN;

    // c1: gather N(p) chunks of row (p,j)
    float4 acc1 = {0,0,0,0};
    #pragma unroll 2
    for (int e = 0; e < dp; ++e) {
        int m = nbsP[e];
        add4(acc1, row[(m << 2) + v]);
    }
    // c2 + c4: gather N(j) chunks of the same row
    float4 acc2 = {0,0,0,0};
    #pragma unroll 2
    for (int e = 0; e < dj; ++e) {
        int m = nbJ[e];
        float4 x = row[(m << 2) + v];
        add4(acc2, x);
        atomicAdd(&c4a[m*17 + v*4 + 0], x.x);
        atomicAdd(&c4a[m*17 + v*4 + 1], x.y);
        atomicAdd(&c4a[m*17 + v*4 + 2], x.z);
        atomicAdd(&c4a[m*17 + v*4 + 3], x.w);
    }
    // diagonal chunks
    float4 xP = row[(p << 2) + v];       // T[p,j,p,:]
    float4 xJ = row[(j << 2) + v];       // T[p,j,j,:]
    size_t opj = (size_t)(p*NN + j) * 72;
    size_t ojp = (size_t)(j*NN + p) * 72;
    out4[opj + 0  + v] = acc1;   // c1[p,j]
    out4[ojp + 4  + v] = acc2;   // c2[j,p]
    out4[opj + 32 + v] = xP;     // c9 [p,j] = T[p,j,p]
    out4[ojp + 36 + v] = xP;     // c10[j,p] = T[p,j,p]
    out4[opj + 40 + v] = xJ;     // c11[p,j] = T[p,j,j]
    out4[ojp + 44 + v] = xJ;     // c12[j,p] = T[p,j,j]

    // c7/c8: row (p,p) dense, one float4 per thread
    {
        const float4* rpp = T4 + (((size_t)(p*NN + p)) << 10);
        float4 x = rpp[t];
        int b = t >> 2, vv = t & 3;
        out4[(size_t)(p*NN + b)*72 + 24 + vv] = x;   // c7[p,b] = T[p,p,b]
        out4[(size_t)(b*NN + p)*72 + 28 + vv] = x;   // c8[b,p] = T[p,p,b]
    }
    __syncthreads();
    // flush c4[.,p]
    for (int idx = t; idx < NN*4; idx += 1024) {
        int k = idx >> 2, vv = idx & 3;
        float4 x4 = {c4a[k*17+vv*4+0], c4a[k*17+vv*4+1],
                     c4a[k*17+vv*4+2], c4a[k*17+vv*4+3]};
        out4[(size_t)(k*NN + p)*72 + 12 + vv] = x4;
    }
}

// ---------------- K_col356: c3, c5, c6 ----------------
// block = (a, b-quarter): 1024 blocks x 256 threads (R2's proven k_col shape).
__global__ __launch_bounds__(256) void k_col356(const float4* __restrict__ T4,
                                                const short* __restrict__ nbr,
                                                const int* __restrict__ deg,
                                                float4* __restrict__ out4) {
    int a = blockIdx.x >> 2;
    int qq = blockIdx.x & 3;
    int t = threadIdx.x;
    int g = t >> 2, v = t & 3;
    int d = deg[a];
    __shared__ short nbs[NN];
    for (int e = t; e < d; e += 256) nbs[e] = nbr[a*NN + e];
    __syncthreads();

    const int b = qq*64 + g;
    const int qslot = qq*256 + t;        // = (b<<2)+v
    float4 a3 = {0,0,0,0}, a5 = {0,0,0,0}, a6 = {0,0,0,0};
    #pragma unroll 2
    for (int e = 0; e < d; ++e) {
        int i = nbs[e];
        float4 x3 = T4[((size_t)(a*NN + i) << 10) + qslot];            // T[a,i,b,:]
        float4 x5 = T4[((size_t)(i*NN + a) << 10) + qslot];            // T[i,a,b,:]
        float4 x6 = T4[((size_t)(i*NN + b) << 10) + (a << 2) + v];     // T[i,b,a,:]
        add4(a3, x3); add4(a5, x5); add4(a6, x6);
    }
    size_t o = (size_t)(a*NN + b) * 72;
    out4[o + 8  + v] = a3;    // c3
    out4[o + 16 + v] = a5;    // c5
    out4[o + 20 + v] = a6;    // c6
}

// ---------------- K_V: v1,v2,v3 from materialized c1,c2,c6 ----------------
__global__ void k_vsum(const float* __restrict__ out_ro,
                       const short* __restrict__ nbr, const int* __restrict__ deg,
                       float* __restrict__ vbuf) {
    int a = blockIdx.x;
    int t = threadIdx.x;            // 256
    int c = t & 15, p = t >> 4;
    int d = deg[a];
    float s1 = 0.f, s2 = 0.f, s3 = 0.f;
    for (int e = p; e < d; e += 16) {
        int b = nbr[a*NN + e];
        size_t o = (size_t)(a*NN + b) * OC;
        s1 += out_ro[o + 0  + c];   // c1
        s2 += out_ro[o + 16 + c];   // c2
        s3 += out_ro[o + 80 + c];   // c6
    }
    __shared__ float red[3][16][17];
    red[0][p][c] = s1; red[1][p][c] = s2; red[2][p][c] = s3;
    __syncthreads();
    if (t < 48) {
        int vv = t >> 4, cc = t & 15;
        float s = 0.f;
        for (int pp = 0; pp < 16; ++pp) s += red[vv][pp][cc];
        vbuf[(vv*NN + a)*CC + cc] = s;
    }
}

// ---------------- K_C: broadcast v's into channels 12..17 ----------------
__global__ __launch_bounds__(256) void k_broadcast(const float4* __restrict__ vb4,
                                                   float4* __restrict__ out4) {
    int a = blockIdx.x;
    int t = threadIdx.x;
    int v = t & 3, bl = t >> 2;
    float4 v1a = vb4[(0*NN + a)*4 + v];
    float4 v2a = vb4[(1*NN + a)*4 + v];
    float4 v3a = vb4[(2*NN + a)*4 + v];
    for (int b = bl; b < NN; b += 64) {
        float4 v1b = vb4[(0*NN + b)*4 + v];
        float4 v2b = vb4[(1*NN + b)*4 + v];
        float4 v3b = vb4[(2*NN + b)*4 + v];
        size_t ob = (size_t)(a*NN + b) * 72;
        out4[ob + 48 + v] = v1a;   // c13
        out4[ob + 52 + v] = v1b;   // c14
        out4[ob + 56 + v] = v2a;   // c15
        out4[ob + 60 + v] = v2b;   // c16
        out4[ob + 64 + v] = v3a;   // c17
        out4[ob + 68 + v] = v3b;   // c18
    }
}

extern "C" void kernel_launch(void* const* d_in, const int* in_sizes, int n_in,
                              void* d_out, int out_size, void* d_ws, size_t ws_size,
                              hipStream_t stream) {
    const float* T = (const float*)d_in[0];   // (256,256,256,16) f32
    const float* A = (const float*)d_in[1];   // (256,256) f32 {0,1} symmetric
    float* out = (float*)d_out;

    // ws: nbr short[256*256] | deg int[256] | vbuf f32[3*256*16]
    char* w = (char*)d_ws;
    short* nbr  = (short*)w;                  w += NN*NN*sizeof(short);
    int*   deg  = (int*)w;                    w += NN*sizeof(int);
    float* vbuf = (float*)w;

    hipLaunchKernelGGL(k_build_nbr, dim3(NN),   dim3(NN),   0, stream, A, nbr, deg);
    hipLaunchKernelGGL(k_slab3,     dim3(NN),   dim3(1024), 0, stream,
                       (const float4*)T, nbr, deg, (float4*)out);
    hipLaunchKernelGGL(k_col356,    dim3(NN*4), dim3(256),  0, stream,
                       (const float4*)T, nbr, deg, (float4*)out);
    hipLaunchKernelGGL(k_vsum,      dim3(NN),   dim3(256),  0, stream, out, nbr, deg, vbuf);
    hipLaunchKernelGGL(k_broadcast, dim3(NN),   dim3(256),  0, stream,
                       (const float4*)vbuf, (float4*)out);
}